// Round 3
// baseline (70.946 us; speedup 1.0000x reference)
//
#include <hip/hip_runtime.h>

// Ball query: for each of NQ=32768 query points g (p_grid), find the first
// K=10 indices i (ascending) of x (N2=8192 points) with
//   d2 = (|g|^2 + |x_i|^2) - 2*dot(g, x_i) <= 0.25^2
// Output (concat, float32): mapping [NQ,K] (index as float, 0 if unfound),
//                           points  [NQ,K,3] (x_i coords, 0 if unfound).
//
// R6 == R5 resubmitted (R5's bench died to "container failed twice" infra
// error before running; kernel audit found no hang/OOB: uniform barriers,
// q<=32767, 6KiB LDS, graph-capture-safe launch).
//
// R5 rationale: R3/R4 timed identical because both stream identical bytes --
// every wave independently re-reads the same x prefix (~330 MB of cache
// requests to a ~10KB hot region). This version shares the candidate stream
// across 4 queries per block via LDS:
//   - 256-pt chunk (3 KB) staged ONCE per block (768 coalesced dwords),
//     double-buffered, ONE barrier per chunk (__syncthreads_and doubles as
//     the done-vote and the buffer fence)
//   - each of the 4 waves evaluates its own query from LDS (3x ds_read_b128
//     per lane, 48B stride -> minimum 2-way bank aliasing = free)
//   - block exits when all 4 waves have found >= K
// Distance math is R3's rounding-locked __fmul_rn/__fadd_rn chain (absmax 0;
// R4's plain-float math got reassociated by fast-math -> absmax 16).
// Index layout/rank math is R4's (base + 4*lane + j), proven correct.

#define BQ_K   10
#define BQ_N2  8192
#define BQ_NQ  32768
#define BQ_R2  0.0625f
#define BQ_CHUNK 256                       // points per chunk
#define BQ_NCHUNK (BQ_N2 / BQ_CHUNK)       // 32
#define BQ_CWORDS (BQ_CHUNK * 3)           // 768 floats per chunk

__device__ __forceinline__ float bq_d2(float gg, float gx, float gy, float gz,
                                       float xv, float yv, float zv) {
    // |x|^2 and dot(g,x) left-to-right, unfused; d2 = (gg + xx) - 2*dot
    // (exactly the reference's association; immune to fast-math).
    const float xx = __fadd_rn(__fadd_rn(__fmul_rn(xv, xv), __fmul_rn(yv, yv)),
                               __fmul_rn(zv, zv));
    const float dt = __fadd_rn(__fadd_rn(__fmul_rn(gx, xv), __fmul_rn(gy, yv)),
                               __fmul_rn(gz, zv));
    return __fsub_rn(__fadd_rn(gg, xx), __fmul_rn(2.0f, dt));
}

__global__ __launch_bounds__(256) void bq_kernel(
    const float* __restrict__ xf,     // [N2*3]
    const float* __restrict__ pg,     // [NQ,3]
    float* __restrict__ map_out,      // [NQ,K]
    float* __restrict__ pts_out)      // [NQ,K,3]
{
    __shared__ __align__(16) float lds[2][BQ_CWORDS];

    const int tid  = threadIdx.x;
    const int lane = tid & 63;
    const int wid  = tid >> 6;                         // 0..3
    const int q    = (int)blockIdx.x * 4 + wid;        // wave per query

    const float gx = pg[q * 3 + 0];
    const float gy = pg[q * 3 + 1];
    const float gz = pg[q * 3 + 2];
    const float gg = __fadd_rn(__fadd_rn(__fmul_rn(gx, gx), __fmul_rn(gy, gy)),
                               __fmul_rn(gz, gz));

    float* __restrict__ mo = map_out + (size_t)q * BQ_K;
    float* __restrict__ po = pts_out + (size_t)q * BQ_K * 3;
    const unsigned long long lt = (1ull << lane) - 1ull;   // lanes below me

    // Prime: stage chunk 0 (768 coalesced dwords across the block).
    {
        const float* src = xf;
        lds[0][tid]       = src[tid];
        lds[0][tid + 256] = src[tid + 256];
        lds[0][tid + 512] = src[tid + 512];
    }
    __syncthreads();

    int found = 0;        // wave-uniform count of valid points seen so far
    int done  = 0;        // wave-uniform
    int cur   = 0;

    for (int c = 0; c < BQ_NCHUNK; ++c) {
        // Stage next chunk into the other buffer (overlaps with compute;
        // made visible to all waves by the __syncthreads_and below).
        if (c + 1 < BQ_NCHUNK) {
            const float* src = xf + (c + 1) * BQ_CWORDS;
            float a = src[tid];
            float b = src[tid + 256];
            float d = src[tid + 512];
            lds[cur ^ 1][tid]       = a;
            lds[cur ^ 1][tid + 256] = b;
            lds[cur ^ 1][tid + 512] = d;
        }

        if (!done) {
            // Lane owns points 4*lane .. 4*lane+3 of this chunk.
            const float* L = lds[cur];
            const float4 f0 = *(const float4*)&L[12 * lane + 0];
            const float4 f1 = *(const float4*)&L[12 * lane + 4];
            const float4 f2 = *(const float4*)&L[12 * lane + 8];

            const float x0 = f0.x, y0 = f0.y, z0 = f0.z;
            const float x1 = f0.w, y1 = f1.x, z1 = f1.y;
            const float x2 = f1.z, y2 = f1.w, z2 = f2.x;
            const float x3 = f2.y, y3 = f2.z, z3 = f2.w;

            const bool v0 = bq_d2(gg, gx, gy, gz, x0, y0, z0) <= BQ_R2;
            const bool v1 = bq_d2(gg, gx, gy, gz, x1, y1, z1) <= BQ_R2;
            const bool v2 = bq_d2(gg, gx, gy, gz, x2, y2, z2) <= BQ_R2;
            const bool v3 = bq_d2(gg, gx, gy, gz, x3, y3, z3) <= BQ_R2;
            const unsigned long long m0 = __ballot(v0);
            const unsigned long long m1 = __ballot(v1);
            const unsigned long long m2 = __ballot(v2);
            const unsigned long long m3 = __ballot(v3);

            if ((m0 | m1 | m2 | m3) != 0ull) {
                // idx = base + 4*lane + j: all lanes below me precede me for
                // every j; own-lane prefix is j-ordered.
                int slot = found + __popcll(m0 & lt) + __popcll(m1 & lt)
                                 + __popcll(m2 & lt) + __popcll(m3 & lt);
                const int idx0 = c * BQ_CHUNK + lane * 4;
                if (v0) {
                    if (slot < BQ_K) {
                        mo[slot] = (float)(idx0 + 0);
                        po[slot * 3 + 0] = x0; po[slot * 3 + 1] = y0; po[slot * 3 + 2] = z0;
                    }
                    ++slot;
                }
                if (v1) {
                    if (slot < BQ_K) {
                        mo[slot] = (float)(idx0 + 1);
                        po[slot * 3 + 0] = x1; po[slot * 3 + 1] = y1; po[slot * 3 + 2] = z1;
                    }
                    ++slot;
                }
                if (v2) {
                    if (slot < BQ_K) {
                        mo[slot] = (float)(idx0 + 2);
                        po[slot * 3 + 0] = x2; po[slot * 3 + 1] = y2; po[slot * 3 + 2] = z2;
                    }
                    ++slot;
                }
                if (v3) {
                    if (slot < BQ_K) {
                        mo[slot] = (float)(idx0 + 3);
                        po[slot * 3 + 0] = x3; po[slot * 3 + 1] = y3; po[slot * 3 + 2] = z3;
                    }
                    ++slot;
                }
                found += __popcll(m0) + __popcll(m1) + __popcll(m2) + __popcll(m3);
                if (found >= BQ_K) done = 1;
            }
        }

        // One barrier per chunk: votes on completion AND fences the staging
        // writes (compiler drains vmcnt/lgkmcnt before s_barrier) AND
        // protects lds[cur] from being overwritten while still being read.
        if (__syncthreads_and(done)) break;
        cur ^= 1;
    }

    // Zero-fill unfound slots (d_out is poisoned 0xAA before every launch).
    const int filled = found < BQ_K ? found : BQ_K;
    if (lane < BQ_K && lane >= filled) {
        mo[lane] = 0.0f;
        po[lane * 3 + 0] = 0.0f;
        po[lane * 3 + 1] = 0.0f;
        po[lane * 3 + 2] = 0.0f;
    }
}

extern "C" void kernel_launch(void* const* d_in, const int* in_sizes, int n_in,
                              void* d_out, int out_size, void* d_ws, size_t ws_size,
                              hipStream_t stream) {
    const float* x  = (const float*)d_in[0];   // (1, 8192, 3) float32
    const float* pg = (const float*)d_in[1];   // (1, 64, 32, 16, 3) float32
    float* out = (float*)d_out;
    float* map_out = out;                          // [NQ*K]
    float* pts_out = out + (size_t)BQ_NQ * BQ_K;   // [NQ*K*3]

    // 4 queries (4 waves) per 256-thread block, sharing the candidate stream.
    bq_kernel<<<BQ_NQ / 4, 256, 0, stream>>>(x, pg, map_out, pts_out);
}